// Round 4
// baseline (271.596 us; speedup 1.0000x reference)
//
#include <hip/hip_runtime.h>
#include <hip/hip_bf16.h>

// AdEx reservoir: out[b][n] = v after 20 steps of
//   t  = min((v - vt[n]) / dt[n], 10)
//   we = beta[n] * exp(t)
//   dv = -alpha[n]*(v + 70) + I[b][n] - we
//   v  = v + 0.1*dv;  v = (v > vt[n]) ? vr[n] : v
// with I = x @ w_in.T.  `w` state is dead (never feeds back, not returned).
//
// R4 changes vs R3:
//  1. Chains paired into float2; the 3 FMAs/step emit v_pk_fma_f32
//     (packed fp32, gfx90a+): main-pipe 12 -> 9 cyc per step-unit.
//  2. Step 0 specialized: v=0 => t2 = tc exactly, e0 = exp2(min(tc,tmax))
//     is batch-independent -> 1 exp per thread instead of kBPB; step 0 is
//     1 fma + cmp + cndmask per chain. Bit-identical to the generic step.
//  3. kBPB 8 -> 16: prologue (param div, w_in loads) amortized 2x.

constexpr int kNeurons = 512;
constexpr int kInputs  = 21;
constexpr int kSteps   = 20;
constexpr int kBPB     = 16;            // chains per thread
constexpr int kPairs   = kBPB / 2;

typedef float v2f __attribute__((ext_vector_type(2)));

__global__ __launch_bounds__(kNeurons) void adex_kernel(
    const float* __restrict__ x,        // [B, 21]
    const float* __restrict__ alpha,    // [512]
    const float* __restrict__ beta,     // [512]
    const float* __restrict__ delta_t,  // [512]
    const float* __restrict__ w_in,     // [512, 21]
    const float* __restrict__ v_thresh, // [512]
    const float* __restrict__ v_reset,  // [512]
    float* __restrict__ out)            // [B, 512]
{
    const int n = threadIdx.x;                       // neuron id
    const long b0 = (long)blockIdx.x * kBPB;         // first batch of block

    const float a  = alpha[n];
    const float be = beta[n];
    const float dt = delta_t[n];
    const float vt = v_thresh[n];
    const float vr = v_reset[n];

    const float kLog2e = 1.44269504088896340736f;
    const float rdt  = kLog2e / dt;
    const float tc   = -vt * rdt;
    const float tmax = 10.0f * kLog2e;
    const float k1   = 1.0f - 0.1f * a;
    const float ka   = 7.0f * a;
    const float bp   = 0.1f * be;

    // Step-0 exp: v=0 -> t2 = fma(0,rdt,tc) = tc exactly; batch-independent.
    const float e0 = __builtin_amdgcn_exp2f(fminf(tc, tmax));

    // w_in row -> registers.
    float w[kInputs];
#pragma unroll
    for (int k = 0; k < kInputs; ++k)
        w[k] = w_in[n * kInputs + k];

    // Input projection (x rows block-uniform -> scalar loads), k2 = 0.1*I - ka.
    float k2[kBPB];
#pragma unroll
    for (int g = 0; g < kBPB; ++g) {
        float I = 0.0f;
#pragma unroll
        for (int k = 0; k < kInputs; ++k)
            I = fmaf(x[(b0 + g) * kInputs + k], w[k], I);
        k2[g] = fmaf(0.1f, I, -ka);
    }

    // Step 0 specialized: vn = fma(-bp, e0, k2)  (== generic step at v=0).
    v2f vv[kPairs], kk[kPairs];
#pragma unroll
    for (int p = 0; p < kPairs; ++p) {
        float vn0 = fmaf(-bp, e0, k2[2 * p]);
        float vn1 = fmaf(-bp, e0, k2[2 * p + 1]);
        vv[p].x = (vn0 > vt) ? vr : vn0;
        vv[p].y = (vn1 > vt) ? vr : vn1;
        kk[p].x = k2[2 * p];
        kk[p].y = k2[2 * p + 1];
    }

    const v2f rdt2  = {rdt, rdt};
    const v2f tc2   = {tc, tc};
    const v2f tmax2 = {tmax, tmax};
    const v2f k12   = {k1, k1};
    const v2f nbp2  = {-bp, -bp};

    // Steps 1..19: 8 packed pairs = 16 independent chains (ILP).
#pragma unroll
    for (int s = 1; s < kSteps; ++s) {
#pragma unroll
        for (int p = 0; p < kPairs; ++p) {
            v2f t2 = __builtin_elementwise_fma(vv[p], rdt2, tc2);   // v_pk_fma
            t2 = __builtin_elementwise_min(t2, tmax2);              // 2x v_min
            v2f e;
            e.x = __builtin_amdgcn_exp2f(t2.x);                     // v_exp_f32
            e.y = __builtin_amdgcn_exp2f(t2.y);                     // v_exp_f32
            v2f inner = __builtin_elementwise_fma(k12, vv[p], kk[p]); // v_pk_fma
            v2f vn = __builtin_elementwise_fma(nbp2, e, inner);       // v_pk_fma
            vv[p].x = (vn.x > vt) ? vr : vn.x;                      // cmp+cndmask
            vv[p].y = (vn.y > vt) ? vr : vn.y;                      // cmp+cndmask
        }
    }

#pragma unroll
    for (int p = 0; p < kPairs; ++p) {
        out[(b0 + 2 * p)     * kNeurons + n] = vv[p].x;             // coalesced
        out[(b0 + 2 * p + 1) * kNeurons + n] = vv[p].y;
    }
}

extern "C" void kernel_launch(void* const* d_in, const int* in_sizes, int n_in,
                              void* d_out, int out_size, void* d_ws, size_t ws_size,
                              hipStream_t stream) {
    const float* x        = (const float*)d_in[0];
    const float* alpha    = (const float*)d_in[1];
    const float* beta     = (const float*)d_in[2];
    const float* delta_t  = (const float*)d_in[3];
    const float* w_in     = (const float*)d_in[4];
    const float* v_thresh = (const float*)d_in[5];
    const float* v_reset  = (const float*)d_in[6];
    float* out = (float*)d_out;

    const int batch = in_sizes[0] / kInputs;         // 65536
    const int grid  = (batch + kBPB - 1) / kBPB;     // 4096 blocks

    adex_kernel<<<grid, kNeurons, 0, stream>>>(
        x, alpha, beta, delta_t, w_in, v_thresh, v_reset, out);
}

// Round 5
// 237.894 us; speedup vs baseline: 1.1417x; 1.1417x over previous
//
#include <hip/hip_runtime.h>
#include <hip/hip_bf16.h>

// AdEx reservoir: out[b][n] = v after 20 steps of
//   t  = min((v - vt[n]) / dt[n], 10)
//   we = beta[n] * exp(t)
//   dv = -alpha[n]*(v + 70) + I[b][n] - we
//   v  = v + 0.1*dv;  v = (v > vt[n]) ? vr[n] : v
// with I = x @ w_in.T.  `w` state is dead (never feeds back, not returned).
//
// R5: state-domain transform. Track u = v*rdt + tc (the exp2 argument):
//   u' = fma(k1, u, c3) - bpr*exp2(u);   spike: u' > 0  -> u = ur
//   c3 = k2*rdt + tc*(1-k1), bpr = 0.1*beta*rdt, ur = vr*rdt + tc
// Per step: exp, fma, fma, cmp-vs-0, cndmask = 4 full-rate ops + 1 trans
// (was 6+1).  The min-clamp provably never binds for steps >= 1:
//   post-step v <= vt always (reset), so next v' <= 0.99*vt + k2 + 0.1|I|
//   < -17 < vt + 10*dt (>= -10) for all parameter draws.  Only step 0
//   (v=0, tc can exceed tmax) needs the clamp -> specialized per-thread e0.
// Output converts back once: v = (u - tc) / rdt.
// R4 lesson kept in mind: v_pk_fma_f32 is issue-packing only (FP32 exec is
// 1 FMA/lane/cyc), so plain scalar fmas are used for clarity.

constexpr int kNeurons = 512;
constexpr int kInputs  = 21;
constexpr int kSteps   = 20;
constexpr int kBPB     = 16;            // chains per thread

__global__ __launch_bounds__(kNeurons) void adex_kernel(
    const float* __restrict__ x,        // [B, 21]
    const float* __restrict__ alpha,    // [512]
    const float* __restrict__ beta,     // [512]
    const float* __restrict__ delta_t,  // [512]
    const float* __restrict__ w_in,     // [512, 21]
    const float* __restrict__ v_thresh, // [512]
    const float* __restrict__ v_reset,  // [512]
    float* __restrict__ out)            // [B, 512]
{
    const int n = threadIdx.x;                       // neuron id
    const long b0 = (long)blockIdx.x * kBPB;         // first batch of block

    const float a  = alpha[n];
    const float be = beta[n];
    const float dt = delta_t[n];
    const float vt = v_thresh[n];
    const float vr = v_reset[n];

    const float kLog2e = 1.44269504088896340736f;
    const float rdt  = kLog2e / dt;        // u = v*rdt + tc
    const float tc   = -vt * rdt;
    const float tmax = 10.0f * kLog2e;
    const float k1   = 1.0f - 0.1f * a;
    const float ka   = 7.0f * a;           // 0.1*alpha*70
    const float bpr  = 0.1f * be * rdt;    // exp coefficient in u-domain
    const float ur   = fmaf(vr, rdt, tc);  // reset value in u-domain

    // Step-0 exp (v=0 -> arg = tc, the only step where the clamp can bind).
    const float f0 = -bpr * __builtin_amdgcn_exp2f(fminf(tc, tmax));

    // c0 = (0.1*I - ka)*rdt + tc          (u after step 0, pre-exp/reset)
    // c3 = c0 - k1*tc                     (per-chain additive constant)
    const float cI  = 0.1f * rdt;
    const float cC0 = fmaf(-ka, rdt, tc);
    const float cC3 = fmaf(-k1, tc, cC0);

    // w_in row -> registers.
    float w[kInputs];
#pragma unroll
    for (int k = 0; k < kInputs; ++k)
        w[k] = w_in[n * kInputs + k];

    // Projection (x rows block-uniform -> scalar loads) + step 0.
    float u[kBPB], c3[kBPB];
#pragma unroll
    for (int g = 0; g < kBPB; ++g) {
        float I = 0.0f;
#pragma unroll
        for (int k = 0; k < kInputs; ++k)
            I = fmaf(x[(b0 + g) * kInputs + k], w[k], I);
        c3[g] = fmaf(cI, I, cC3);
        float u1 = fmaf(cI, I, cC0) + f0;      // step-0 update
        u[g] = (u1 > 0.0f) ? ur : u1;          // step-0 spike/reset
    }

    // Steps 1..19: 16 independent chains, 4 full-rate ops + 1 exp each.
#pragma unroll
    for (int s = 1; s < kSteps; ++s) {
#pragma unroll
        for (int g = 0; g < kBPB; ++g) {
            float e  = __builtin_amdgcn_exp2f(u[g]);        // v_exp_f32
            float un = fmaf(-bpr, e, fmaf(k1, u[g], c3[g])); // 2x v_fma
            u[g] = (un > 0.0f) ? ur : un;                   // cmp0 + cndmask
        }
    }

    // Convert back: v = (u - tc) / rdt = u*inv - tc*inv.
    const float inv = dt * (1.0f / kLog2e) * 1.0f;  // 1/rdt
    const float oc  = -tc * inv;
#pragma unroll
    for (int g = 0; g < kBPB; ++g)
        out[(b0 + g) * kNeurons + n] = fmaf(u[g], inv, oc); // coalesced

}

extern "C" void kernel_launch(void* const* d_in, const int* in_sizes, int n_in,
                              void* d_out, int out_size, void* d_ws, size_t ws_size,
                              hipStream_t stream) {
    const float* x        = (const float*)d_in[0];
    const float* alpha    = (const float*)d_in[1];
    const float* beta     = (const float*)d_in[2];
    const float* delta_t  = (const float*)d_in[3];
    const float* w_in     = (const float*)d_in[4];
    const float* v_thresh = (const float*)d_in[5];
    const float* v_reset  = (const float*)d_in[6];
    float* out = (float*)d_out;

    const int batch = in_sizes[0] / kInputs;         // 65536
    const int grid  = (batch + kBPB - 1) / kBPB;     // 4096 blocks

    adex_kernel<<<grid, kNeurons, 0, stream>>>(
        x, alpha, beta, delta_t, w_in, v_thresh, v_reset, out);
}